// Round 5
// baseline (13826.245 us; speedup 1.0000x reference)
//
#include <hip/hip_runtime.h>
#include <hip/hip_bf16.h>

typedef unsigned short ushort_t;
typedef unsigned int uint_t;
typedef _Float16 h2v __attribute__((ext_vector_type(2)));
typedef uint_t uvec32 __attribute__((ext_vector_type(32)));

#define N_NOTES 2000

__device__ __forceinline__ float sigm(float x) { return 1.0f / (1.0f + __expf(-x)); }
__device__ __forceinline__ float tanhc(float x) {
    x = fminf(fmaxf(x, -15.f), 15.f);
    float e = __expf(2.f * x);
    return (e - 1.f) / (e + 1.f);
}
__device__ __forceinline__ uint_t pk2(float a, float b) {
    h2v h; h[0] = (_Float16)a; h[1] = (_Float16)b;
    return __builtin_bit_cast(uint_t, h);
}

#if __has_builtin(__builtin_amdgcn_fdot2)
__device__ __forceinline__ float fdot2f(uint_t a, uint_t b, float c) {
    return __builtin_amdgcn_fdot2(__builtin_bit_cast(h2v, a), __builtin_bit_cast(h2v, b), c, false);
}
#else
__device__ __forceinline__ float fdot2f(uint_t a, uint_t b, float c) {
    h2v x = __builtin_bit_cast(h2v, a), y = __builtin_bit_cast(h2v, b);
    return c + (float)x[0] * (float)y[0] + (float)x[1] * (float)y[1];
}
#endif

// Raw barrier: lgkm-only drain (keeps global prefetch loads in flight across it).
#define BAR() do { \
    asm volatile("s_waitcnt lgkmcnt(0)" ::: "memory"); \
    __builtin_amdgcn_s_barrier(); \
    asm volatile("" ::: "memory"); \
} while (0)
#define LGKM0() asm volatile("s_waitcnt lgkmcnt(0)" ::: "memory")

// ---------------- perform_z = relu(exp_W @ perf + exp_b) ----------------
__global__ __launch_bounds__(64) void pz_kernel(const float* __restrict__ expW,
                                                const float* __restrict__ expb,
                                                const float* __restrict__ perf,
                                                float* __restrict__ pz) {
    int t = threadIdx.x;
    float acc = expb[t];
#pragma unroll
    for (int k = 0; k < 16; k++) acc += expW[t * 16 + k] * perf[k];
    pz[t] = fmaxf(acc, 0.f);
}

// ---------------- opre: 16 notes per block ----------------
__global__ __launch_bounds__(512, 2) void opre_kernel(
    const float* __restrict__ oWih, const float* __restrict__ obih, const float* __restrict__ obhh,
    const float* __restrict__ ne, const float* __restrict__ be, const float* __restrict__ me,
    const float* __restrict__ fcb, const float* __restrict__ pz,
    const int* __restrict__ bn, const int* __restrict__ mn, float* __restrict__ opre) {
    const int i0 = blockIdx.x * 16;
    const int j = threadIdx.x;
    __shared__ float xs[16][256];
    __shared__ float xm[16][128];
    __shared__ float pz_l[64];
    __shared__ float fcb_l[10];
    if (j < 64) pz_l[j] = pz[j];
    if (j < 10) fcb_l[j] = fcb[j];
    const int bn0 = bn[0], mn0 = mn[0];
    __syncthreads();
    const float* w = oWih + j * 715;
    float tail = obih[j] + obhh[j];
#pragma unroll
    for (int r = 0; r < 10; r++) tail += w[641 + r] * fcb_l[r];
#pragma unroll 8
    for (int k = 0; k < 64; k++) tail += w[651 + k] * pz_l[k];
    float acc[16];
#pragma unroll
    for (int m = 0; m < 16; m++) acc[m] = tail;
    for (int t = j; t < 16 * 256; t += 512) xs[t >> 8][t & 255] = ne[i0 * 256 + t];
    __syncthreads();
#pragma unroll 4
    for (int k = 0; k < 256; k++) {
        float wv = w[k];
#pragma unroll
        for (int m = 0; m < 16; m++) acc[m] += wv * xs[m][k];
    }
    __syncthreads();
    for (int t = j; t < 16 * 256; t += 512) {
        int m = t >> 8, k = t & 255;
        xs[m][k] = be[(bn[i0 + m] - bn0) * 256 + k];
    }
    __syncthreads();
#pragma unroll 4
    for (int k = 0; k < 256; k++) {
        float wv = w[256 + k];
#pragma unroll
        for (int m = 0; m < 16; m++) acc[m] += wv * xs[m][k];
    }
    __syncthreads();
    for (int t = j; t < 16 * 128; t += 512) {
        int m = t >> 7, k = t & 127;
        xm[m][k] = me[(mn[i0 + m] - mn0) * 128 + k];
    }
    __syncthreads();
#pragma unroll 4
    for (int k = 0; k < 128; k++) {
        float wv = w[512 + k];
#pragma unroll
        for (int m = 0; m < 16; m++) acc[m] += wv * xm[m][k];
    }
#pragma unroll
    for (int m = 0; m < 16; m++) opre[(i0 + m) * 512 + j] = acc[m];
}

// ---------------- tpre: same structure ----------------
__global__ __launch_bounds__(512, 2) void tpre_kernel(
    const float* __restrict__ tWih, const float* __restrict__ tbih, const float* __restrict__ tbhh,
    const float* __restrict__ be, const float* __restrict__ me, const float* __restrict__ ri,
    const float* __restrict__ pz, const int* __restrict__ bn, const int* __restrict__ mn,
    float* __restrict__ tpre) {
    const int i0 = blockIdx.x * 16;
    const int j = threadIdx.x;
    __shared__ float xs[16][256];
    __shared__ float xm[16][128];
    __shared__ float xr[16][8];
    __shared__ float pz_l[64];
    if (j < 64) pz_l[j] = pz[j];
    const int bn0 = bn[0], mn0 = mn[0];
    __syncthreads();
    const float* w = tWih + j * 467;
    float tail = tbih[j] + tbhh[j];
#pragma unroll 8
    for (int k = 0; k < 64; k++) tail += w[403 + k] * pz_l[k];
    float acc[16];
#pragma unroll
    for (int m = 0; m < 16; m++) acc[m] = tail;
    for (int t = j; t < 16 * 256; t += 512) {
        int m = t >> 8, k = t & 255;
        xs[m][k] = be[(bn[i0 + m] - bn0) * 256 + k];
    }
    if (j < 128) {
        int m = j >> 3, k = j & 7;
        xr[m][k] = ri[(bn[i0 + m] - bn0) * 8 + k];
    }
    __syncthreads();
#pragma unroll 4
    for (int k = 0; k < 256; k++) {
        float wv = w[k];
#pragma unroll
        for (int m = 0; m < 16; m++) acc[m] += wv * xs[m][k];
    }
#pragma unroll
    for (int k = 0; k < 8; k++) {
        float wv = w[385 + k];
#pragma unroll
        for (int m = 0; m < 16; m++) acc[m] += wv * xr[m][k];
    }
    __syncthreads();
    for (int t = j; t < 16 * 128; t += 512) {
        int m = t >> 7, k = t & 127;
        xm[m][k] = me[(mn[i0 + m] - mn0) * 128 + k];
    }
    __syncthreads();
#pragma unroll 4
    for (int k = 0; k < 128; k++) {
        float wv = w[256 + k];
#pragma unroll
        for (int m = 0; m < 16; m++) acc[m] += wv * xm[m][k];
    }
#pragma unroll
    for (int m = 0; m < 16; m++) tpre[(i0 + m) * 512 + j] = acc[m];
}

// fc + sim for one note, executed by ONE wave with NO big butterfly:
// lane = (r = lane&15 -> output idx, cch = lane>>4 -> 32-col chunk), 2 shfl levels.
__device__ __forceinline__ void fc_sim(
    const uint_t* fhp, int lane,
    const uint_t* fcw_pk, const float* attnW_lds, const float* attnb_lds,
    const float* attncv_lds, const float* fcb_lds,
    volatile float* ofc_tmp, volatile float* t_tmp,
    float* out_ring, float* sim_ring, float* __restrict__ out_g,
    int note, bool write_ring, bool write_out, float tempo_val) {
    const int r = lane & 15;
    const int cch = lane >> 4;
    float a0 = 0.f, a1 = 0.f, a2 = 0.f, a3 = 0.f;
    if (r < 10) {
        const uint4* fv = (const uint4*)fhp + (cch << 2);
        const uint4* wv = (const uint4*)(fcw_pk + r * 68) + (cch << 2);
#pragma unroll
        for (int q = 0; q < 4; q++) {
            uint4 a = wv[q]; uint4 b = fv[q];
            a0 = fdot2f(a.x, b.x, a0);
            a1 = fdot2f(a.y, b.y, a1);
            a2 = fdot2f(a.z, b.z, a2);
            a3 = fdot2f(a.w, b.w, a3);
        }
    }
    float acc = (a0 + a1) + (a2 + a3);
    acc += __shfl_xor(acc, 16);
    acc += __shfl_xor(acc, 32);
    float ofc = acc + fcb_lds[r];
    if (lane < 10) ofc_tmp[lane] = ofc;
    LGKM0();
    if (lane < 10) {
        float a = attnb_lds[lane];
#pragma unroll
        for (int c = 0; c < 10; c++) a += attnW_lds[lane * 10 + c] * ofc_tmp[c];
        t_tmp[lane] = tanhc(a) * attncv_lds[lane];
    }
    LGKM0();
    if (lane == 0) {
        float s = 0.f;
#pragma unroll
        for (int c = 0; c < 10; c++) s += t_tmp[c];
        sim_ring[note & 255] = s;
    }
    if (lane < 10) {
        if (write_ring) out_ring[(note & 255) * 10 + lane] = ofc;
        if (write_out) out_g[note * 11 + 1 + lane] = ofc;
    }
    if (write_out && lane == 0) out_g[note * 11] = tempo_val;
}

// ---------------- 2000-step serial scan: one 1024-thread workgroup ----------------
// Thread j: row = j&511, half = j>>9. Weights in ext_vector SSA values (32 uints
// each) -> guaranteed non-alloca, constant-indexed only -> registers.
__global__ __launch_bounds__(1024, 4) void seq_kernel(
    const float* __restrict__ oWih, const float* __restrict__ oWhh,
    const float* __restrict__ tWih, const float* __restrict__ tWhh,
    const float* __restrict__ fcW, const float* __restrict__ fcb,
    const float* __restrict__ tfcW, const float* __restrict__ tfcb,
    const float* __restrict__ attnW, const float* __restrict__ attnb,
    const float* __restrict__ attncv,
    const int* __restrict__ bn_g,
    const float* __restrict__ opre, const float* __restrict__ tpre,
    float* __restrict__ out) {
    const int j = threadIdx.x;
    const int row = j & 511;
    const int half = j >> 9;
    const int lane = j & 63;

    __shared__ float zpart[2 * 512];
    __shared__ float tpart[2 * 512];
    __shared__ __align__(16) uint_t fh_pk[2 * 64];   // double-buffered packed h
    __shared__ __align__(16) uint_t th_pk[64];
    __shared__ __align__(16) uint_t fcw_pk[10 * 68]; // padded stride 68
    __shared__ __align__(16) uint_t tfcw_pk[64];
    __shared__ float attnW_lds[100];
    __shared__ float attnb_lds[10], attncv_lds[10], fcb_lds[10];
    __shared__ uint_t rn_pk[5];
    __shared__ float rn_tmp[10];
    __shared__ float tempo_lds[1];
    __shared__ float ofc_tmpD[10], t_tmpD[10], ofc_tmpE[10], t_tmpE[10];
    __shared__ float out_ring[256 * 10];
    __shared__ float sim_ring[256];

    // ---- stage small tensors ----
    for (int idx = j; idx < 640; idx += 1024) {
        int r = idx >> 6, k = idx & 63;
        fcw_pk[r * 68 + k] = pk2(fcW[r * 128 + 2 * k], fcW[r * 128 + 2 * k + 1]);
    }
    if (j < 64) tfcw_pk[j] = pk2(tfcW[2 * j], tfcW[2 * j + 1]);
    if (j < 100) attnW_lds[j] = attnW[j];
    if (j < 10) {
        attnb_lds[j] = attnb[j];
        attncv_lds[j] = attncv[j];
        fcb_lds[j] = fcb[j];
    }
    if (j < 5) rn_pk[j] = 0;
    if (j < 128) fh_pk[j] = 0;
    if (j < 64) th_pk[j] = 0;
    if (j == 0) tempo_lds[0] = 0.f;
    __syncthreads();

    // ---- per-thread half-row weights (ext_vector SSA -> registers) ----
    const int cbase = half * 64;
    float c1[10];
#pragma unroll
    for (int r = 0; r < 10; r++) c1[r] = oWih[row * 715 + 641 + r];
    float d0 = 0.f;
#pragma unroll
    for (int r = 0; r < 10; r++) d0 += c1[r] * fcb_lds[r];
    const float ocol = oWih[row * 715 + 640];
    const float twc384 = tWih[row * 467 + 384];

    uvec32 w2;
    {
        const float* owr = oWhh + row * 128 + cbase;
#pragma unroll
        for (int q = 0; q < 32; q++) {
            float a = owr[2 * q];
            float b = owr[2 * q + 1];
#pragma unroll
            for (int r = 0; r < 10; r++) {
                a += c1[r] * fcW[r * 128 + cbase + 2 * q];
                b += c1[r] * fcW[r * 128 + cbase + 2 * q + 1];
            }
            w2[q] = pk2(a, b);
        }
    }
    uvec32 t2;
    {
        const float* twr = tWhh + row * 128 + cbase;
#pragma unroll
        for (int q = 0; q < 32; q++) {
            float a = twr[2 * q]     + twc384 * tfcW[cbase + 2 * q];
            float b = twr[2 * q + 1] + twc384 * tfcW[cbase + 2 * q + 1];
            t2[q] = pk2(a, b);
        }
    }
    uint_t twcp[5];
#pragma unroll
    for (int r = 0; r < 5; r++)
        twcp[r] = pk2(tWih[row * 467 + 393 + 2 * r], tWih[row * 467 + 393 + 2 * r + 1]);
    const float const_t = twc384 * tfcb[0];

    // ---- recurrence state ----
    float fc0 = 0.f, fc1 = 0.f, tc0 = 0.f, tc1 = 0.f;  // wave-0 lanes
    int prev_end = 0;                                   // wave-0
    int bn_cur = bn_g[0];
    int bn_nxt = bn_g[1];
    bool bnd_cur = true;
    float pre_cur = half ? tpre[row] : opre[row];
    __syncthreads();

#pragma unroll 1
    for (int i = 0; i < N_NOTES; ++i) {
        const bool bnd_nxt = (bn_nxt > bn_cur);
        const int par = i & 1;
        // ---- depth-1 prefetch (raw barriers never drain vmcnt) ----
        float pre_nxt = 0.f;
        int bn_nxt2 = bn_nxt;
        if (i + 1 < N_NOTES) {
            if (half == 0) pre_nxt = opre[(i + 1) * 512 + row];
            else if (bnd_nxt) pre_nxt = tpre[(i + 1) * 512 + row];
            if (i + 2 < N_NOTES) bn_nxt2 = bn_g[i + 2];
        }
        // ---- P1: half-row matvec partials ----
        {
            const uint4* fp = (const uint4*)(fh_pk + ((par ^ 1) << 6)) + (half << 3);
            float a0 = 0.f, a1 = 0.f, a2 = 0.f, a3 = 0.f;
#pragma unroll
            for (int q = 0; q < 8; q++) {
                uint4 v = fp[q];
                a0 = fdot2f(w2[4 * q + 0], v.x, a0);
                a1 = fdot2f(w2[4 * q + 1], v.y, a1);
                a2 = fdot2f(w2[4 * q + 2], v.z, a2);
                a3 = fdot2f(w2[4 * q + 3], v.w, a3);
            }
            float zb = 0.f;
            if (half == 0) {
                zb = pre_cur + ocol * tempo_lds[0];
                if (i == 0) zb -= d0;
            }
            zpart[(half << 9) + row] = ((a0 + a1) + (a2 + a3)) + zb;
        }
        if (bnd_cur) {
            const uint4* tp = (const uint4*)th_pk + (half << 3);
            float a0 = 0.f, a1 = 0.f, a2 = 0.f, a3 = 0.f;
#pragma unroll
            for (int q = 0; q < 8; q++) {
                uint4 v = tp[q];
                a0 = fdot2f(t2[4 * q + 0], v.x, a0);
                a1 = fdot2f(t2[4 * q + 1], v.y, a1);
                a2 = fdot2f(t2[4 * q + 2], v.z, a2);
                a3 = fdot2f(t2[4 * q + 3], v.w, a3);
            }
            float ztb;
            if (half == 0) {
                ztb = (i == 0) ? 0.f : const_t;
#pragma unroll
                for (int r = 0; r < 5; r++) ztb = fdot2f(twcp[r], rn_pk[r], ztb);
            } else {
                ztb = pre_cur;
            }
            tpart[(half << 9) + row] = ((a0 + a1) + (a2 + a3)) + ztb;
        }
        BAR();  // BAR1: partials visible
        // ---- P2: wave0 gates; wave1 deferred fc/sim/out for note i-1 ----
        if (j < 64) {
            const int u0 = 2 * lane;
            float2 x0 = *(const float2*)&zpart[u0];
            float2 y0 = *(const float2*)&zpart[512 + u0];
            float2 x1 = *(const float2*)&zpart[128 + u0];
            float2 y1 = *(const float2*)&zpart[640 + u0];
            float2 x2 = *(const float2*)&zpart[256 + u0];
            float2 y2 = *(const float2*)&zpart[768 + u0];
            float2 x3 = *(const float2*)&zpart[384 + u0];
            float2 y3 = *(const float2*)&zpart[896 + u0];
            float zi0 = x0.x + y0.x, zi1 = x0.y + y0.y;
            float zf0 = x1.x + y1.x, zf1 = x1.y + y1.y;
            float zg0 = x2.x + y2.x, zg1 = x2.y + y2.y;
            float zo0 = x3.x + y3.x, zo1 = x3.y + y3.y;
            fc0 = sigm(zf0) * fc0 + sigm(zi0) * tanhc(zg0);
            fc1 = sigm(zf1) * fc1 + sigm(zi1) * tanhc(zg1);
            float h0 = sigm(zo0) * tanhc(fc0);
            float h1 = sigm(zo1) * tanhc(fc1);
            fh_pk[(par << 6) + lane] = pk2(h0, h1);
            if (bnd_cur) {
                float2 p0 = *(const float2*)&tpart[u0];
                float2 q0 = *(const float2*)&tpart[512 + u0];
                float2 p1 = *(const float2*)&tpart[128 + u0];
                float2 q1 = *(const float2*)&tpart[640 + u0];
                float2 p2 = *(const float2*)&tpart[256 + u0];
                float2 q2 = *(const float2*)&tpart[768 + u0];
                float2 p3 = *(const float2*)&tpart[384 + u0];
                float2 q3 = *(const float2*)&tpart[896 + u0];
                float ti0 = p0.x + q0.x, ti1 = p0.y + q0.y;
                float tf0 = p1.x + q1.x, tf1 = p1.y + q1.y;
                float tg0 = p2.x + q2.x, tg1 = p2.y + q2.y;
                float to0 = p3.x + q3.x, to1 = p3.y + q3.y;
                tc0 = sigm(tf0) * tc0 + sigm(ti0) * tanhc(tg0);
                tc1 = sigm(tf1) * tc1 + sigm(ti1) * tanhc(tg1);
                float g0 = sigm(to0) * tanhc(tc0);
                float g1 = sigm(to1) * tanhc(tc1);
                th_pk[lane] = pk2(g0, g1);
            }
        } else if (j < 128 && i > 0) {
            fc_sim(fh_pk + ((par ^ 1) << 6), lane, fcw_pk, attnW_lds, attnb_lds,
                   attncv_lds, fcb_lds, ofc_tmpD, t_tmpD, out_ring, sim_ring, out,
                   i - 1, !bnd_cur, true, tempo_lds[0]);
        }
        BAR();  // BAR2
        // ---- P3 (only near boundaries): wave0 eager fc + attention; wave2 tempo ----
        if (bnd_cur || bnd_nxt) {
            if (j < 64) {
                if (bnd_cur) prev_end = i;
                if (bnd_nxt && (i + 1 < N_NOTES)) {
                    fc_sim(fh_pk + (par << 6), lane, fcw_pk, attnW_lds, attnb_lds,
                           attncv_lds, fcb_lds, ofc_tmpE, t_tmpE, out_ring, sim_ring, out,
                           i, true, false, 0.f);
                    LGKM0();
                    const int L = i + 1 - prev_end;
                    float m = -1e30f;
                    for (int b = lane; b < L; b += 64) m = fmaxf(m, sim_ring[(prev_end + b) & 255]);
#pragma unroll
                    for (int d = 32; d >= 1; d >>= 1) m = fmaxf(m, __shfl_xor(m, d));
                    float es = 0.f;
                    float accv[10];
#pragma unroll
                    for (int r = 0; r < 10; r++) accv[r] = 0.f;
                    for (int b = lane; b < L; b += 64) {
                        int idx = (prev_end + b) & 255;
                        float e = __expf(sim_ring[idx] - m);
                        es += e;
#pragma unroll
                        for (int r = 0; r < 10; r++) accv[r] += e * out_ring[idx * 10 + r];
                    }
#pragma unroll
                    for (int d = 32; d >= 1; d >>= 1) {
                        es += __shfl_xor(es, d);
#pragma unroll
                        for (int r = 0; r < 10; r++) accv[r] += __shfl_xor(accv[r], d);
                    }
                    float inv = 1.f / fmaxf(es, 1e-20f);
                    if (lane < 10) rn_tmp[lane] = accv[lane] * inv;
                    LGKM0();
                    if (lane < 5) rn_pk[lane] = pk2(rn_tmp[2 * lane], rn_tmp[2 * lane + 1]);
                }
            } else if (j >= 128 && j < 192 && bnd_cur) {
                // wave2: tempo = tfcW . th + tfcb  (16 lanes x 4 packed uints)
                float acc = 0.f;
                if (lane < 16) {
#pragma unroll
                    for (int m2 = 0; m2 < 4; m2++)
                        acc = fdot2f(tfcw_pk[lane * 4 + m2], th_pk[lane * 4 + m2], acc);
                }
                acc += __shfl_xor(acc, 8);
                acc += __shfl_xor(acc, 4);
                acc += __shfl_xor(acc, 2);
                acc += __shfl_xor(acc, 1);
                if (lane == 0) tempo_lds[0] = acc + tfcb[0];
            }
            BAR();  // BAR3: rn/tempo visible for next P1
        }
        pre_cur = pre_nxt;
        bn_cur = bn_nxt;
        bn_nxt = bn_nxt2;
        bnd_cur = bnd_nxt;
    }
    // epilogue: deferred job for the final note
    if (j >= 64 && j < 128) {
        fc_sim(fh_pk + (((N_NOTES - 1) & 1) << 6), lane, fcw_pk, attnW_lds, attnb_lds,
               attncv_lds, fcb_lds, ofc_tmpD, t_tmpD, out_ring, sim_ring, out,
               N_NOTES - 1, false, true, tempo_lds[0]);
    }
}

extern "C" void kernel_launch(void* const* d_in, const int* in_sizes, int n_in,
                              void* d_out, int out_size, void* d_ws, size_t ws_size,
                              hipStream_t stream) {
    (void)in_sizes; (void)n_in; (void)out_size; (void)ws_size;
    const float* ne     = (const float*)d_in[0];
    const float* be     = (const float*)d_in[1];
    const float* me     = (const float*)d_in[2];
    const float* ri     = (const float*)d_in[3];
    const float* perf   = (const float*)d_in[4];
    const int*   bn     = (const int*)d_in[5];
    const int*   mn     = (const int*)d_in[6];
    const float* expW   = (const float*)d_in[7];
    const float* expb   = (const float*)d_in[8];
    const float* tWih   = (const float*)d_in[9];
    const float* tWhh   = (const float*)d_in[10];
    const float* tbih   = (const float*)d_in[11];
    const float* tbhh   = (const float*)d_in[12];
    const float* tfcW   = (const float*)d_in[13];
    const float* tfcb   = (const float*)d_in[14];
    const float* attnW  = (const float*)d_in[15];
    const float* attnb  = (const float*)d_in[16];
    const float* attncv = (const float*)d_in[17];
    const float* oWih   = (const float*)d_in[18];
    const float* oWhh   = (const float*)d_in[19];
    const float* obih   = (const float*)d_in[20];
    const float* obhh   = (const float*)d_in[21];
    const float* fcW    = (const float*)d_in[22];
    const float* fcb    = (const float*)d_in[23];

    float* pz   = (float*)d_ws;
    float* opre = pz + 64;
    float* tpre = opre + N_NOTES * 512;
    float* out  = (float*)d_out;

    pz_kernel<<<1, 64, 0, stream>>>(expW, expb, perf, pz);
    opre_kernel<<<N_NOTES / 16, 512, 0, stream>>>(oWih, obih, obhh, ne, be, me, fcb, pz, bn, mn, opre);
    tpre_kernel<<<N_NOTES / 16, 512, 0, stream>>>(tWih, tbih, tbhh, be, me, ri, pz, bn, mn, tpre);
    seq_kernel<<<1, 1024, 0, stream>>>(oWih, oWhh, tWih, tWhh, fcW, fcb, tfcW, tfcb,
                                       attnW, attnb, attncv, bn, opre, tpre, out);
}

// Round 7
// 3413.084 us; speedup vs baseline: 4.0510x; 4.0510x over previous
//
#include <hip/hip_runtime.h>
#include <hip/hip_bf16.h>

typedef unsigned short ushort_t;
typedef unsigned int uint_t;
typedef _Float16 h2v __attribute__((ext_vector_type(2)));
typedef uint_t uvec32 __attribute__((ext_vector_type(32)));

#define N_NOTES 2000

__device__ __forceinline__ float sigm(float x) { return 1.0f / (1.0f + __expf(-x)); }
__device__ __forceinline__ float tanhc(float x) {
    x = fminf(fmaxf(x, -15.f), 15.f);
    float e = __expf(2.f * x);
    return (e - 1.f) / (e + 1.f);
}
__device__ __forceinline__ uint_t pk2(float a, float b) {
    h2v h; h[0] = (_Float16)a; h[1] = (_Float16)b;
    return __builtin_bit_cast(uint_t, h);
}

#if __has_builtin(__builtin_amdgcn_fdot2)
__device__ __forceinline__ float fdot2f(uint_t a, uint_t b, float c) {
    return __builtin_amdgcn_fdot2(__builtin_bit_cast(h2v, a), __builtin_bit_cast(h2v, b), c, false);
}
#else
__device__ __forceinline__ float fdot2f(uint_t a, uint_t b, float c) {
    h2v x = __builtin_bit_cast(h2v, a), y = __builtin_bit_cast(h2v, b);
    return c + (float)x[0] * (float)y[0] + (float)x[1] * (float)y[1];
}
#endif

// Raw barrier: lgkm-only drain (keeps global prefetch loads in flight across it).
#define BAR() do { \
    asm volatile("s_waitcnt lgkmcnt(0)" ::: "memory"); \
    __builtin_amdgcn_s_barrier(); \
    asm volatile("" ::: "memory"); \
} while (0)
#define LGKM0() asm volatile("s_waitcnt lgkmcnt(0)" ::: "memory")

// ---------------- perform_z = relu(exp_W @ perf + exp_b) ----------------
__global__ __launch_bounds__(64) void pz_kernel(const float* __restrict__ expW,
                                                const float* __restrict__ expb,
                                                const float* __restrict__ perf,
                                                float* __restrict__ pz) {
    int t = threadIdx.x;
    float acc = expb[t];
#pragma unroll
    for (int k = 0; k < 16; k++) acc += expW[t * 16 + k] * perf[k];
    pz[t] = fmaxf(acc, 0.f);
}

// ---------------- opre: 16 notes per block ----------------
__global__ __launch_bounds__(512, 2) void opre_kernel(
    const float* __restrict__ oWih, const float* __restrict__ obih, const float* __restrict__ obhh,
    const float* __restrict__ ne, const float* __restrict__ be, const float* __restrict__ me,
    const float* __restrict__ fcb, const float* __restrict__ pz,
    const int* __restrict__ bn, const int* __restrict__ mn, float* __restrict__ opre) {
    const int i0 = blockIdx.x * 16;
    const int j = threadIdx.x;
    __shared__ float xs[16][256];
    __shared__ float xm[16][128];
    __shared__ float pz_l[64];
    __shared__ float fcb_l[10];
    if (j < 64) pz_l[j] = pz[j];
    if (j < 10) fcb_l[j] = fcb[j];
    const int bn0 = bn[0], mn0 = mn[0];
    __syncthreads();
    const float* w = oWih + j * 715;
    float tail = obih[j] + obhh[j];
#pragma unroll
    for (int r = 0; r < 10; r++) tail += w[641 + r] * fcb_l[r];
#pragma unroll 8
    for (int k = 0; k < 64; k++) tail += w[651 + k] * pz_l[k];
    float acc[16];
#pragma unroll
    for (int m = 0; m < 16; m++) acc[m] = tail;
    for (int t = j; t < 16 * 256; t += 512) xs[t >> 8][t & 255] = ne[i0 * 256 + t];
    __syncthreads();
#pragma unroll 4
    for (int k = 0; k < 256; k++) {
        float wv = w[k];
#pragma unroll
        for (int m = 0; m < 16; m++) acc[m] += wv * xs[m][k];
    }
    __syncthreads();
    for (int t = j; t < 16 * 256; t += 512) {
        int m = t >> 8, k = t & 255;
        xs[m][k] = be[(bn[i0 + m] - bn0) * 256 + k];
    }
    __syncthreads();
#pragma unroll 4
    for (int k = 0; k < 256; k++) {
        float wv = w[256 + k];
#pragma unroll
        for (int m = 0; m < 16; m++) acc[m] += wv * xs[m][k];
    }
    __syncthreads();
    for (int t = j; t < 16 * 128; t += 512) {
        int m = t >> 7, k = t & 127;
        xm[m][k] = me[(mn[i0 + m] - mn0) * 128 + k];
    }
    __syncthreads();
#pragma unroll 4
    for (int k = 0; k < 128; k++) {
        float wv = w[512 + k];
#pragma unroll
        for (int m = 0; m < 16; m++) acc[m] += wv * xm[m][k];
    }
#pragma unroll
    for (int m = 0; m < 16; m++) opre[(i0 + m) * 512 + j] = acc[m];
}

// ---------------- tpre: same structure ----------------
__global__ __launch_bounds__(512, 2) void tpre_kernel(
    const float* __restrict__ tWih, const float* __restrict__ tbih, const float* __restrict__ tbhh,
    const float* __restrict__ be, const float* __restrict__ me, const float* __restrict__ ri,
    const float* __restrict__ pz, const int* __restrict__ bn, const int* __restrict__ mn,
    float* __restrict__ tpre) {
    const int i0 = blockIdx.x * 16;
    const int j = threadIdx.x;
    __shared__ float xs[16][256];
    __shared__ float xm[16][128];
    __shared__ float xr[16][8];
    __shared__ float pz_l[64];
    if (j < 64) pz_l[j] = pz[j];
    const int bn0 = bn[0], mn0 = mn[0];
    __syncthreads();
    const float* w = tWih + j * 467;
    float tail = tbih[j] + tbhh[j];
#pragma unroll 8
    for (int k = 0; k < 64; k++) tail += w[403 + k] * pz_l[k];
    float acc[16];
#pragma unroll
    for (int m = 0; m < 16; m++) acc[m] = tail;
    for (int t = j; t < 16 * 256; t += 512) {
        int m = t >> 8, k = t & 255;
        xs[m][k] = be[(bn[i0 + m] - bn0) * 256 + k];
    }
    if (j < 128) {
        int m = j >> 3, k = j & 7;
        xr[m][k] = ri[(bn[i0 + m] - bn0) * 8 + k];
    }
    __syncthreads();
#pragma unroll 4
    for (int k = 0; k < 256; k++) {
        float wv = w[k];
#pragma unroll
        for (int m = 0; m < 16; m++) acc[m] += wv * xs[m][k];
    }
#pragma unroll
    for (int k = 0; k < 8; k++) {
        float wv = w[385 + k];
#pragma unroll
        for (int m = 0; m < 16; m++) acc[m] += wv * xr[m][k];
    }
    __syncthreads();
    for (int t = j; t < 16 * 128; t += 512) {
        int m = t >> 7, k = t & 127;
        xm[m][k] = me[(mn[i0 + m] - mn0) * 128 + k];
    }
    __syncthreads();
#pragma unroll 4
    for (int k = 0; k < 128; k++) {
        float wv = w[256 + k];
#pragma unroll
        for (int m = 0; m < 16; m++) acc[m] += wv * xm[m][k];
    }
#pragma unroll
    for (int m = 0; m < 16; m++) tpre[(i0 + m) * 512 + j] = acc[m];
}

// fc + sim for one note by ONE wave, as a MACRO so all LDS arrays are referenced
// directly (no generic float* params -> no addrspace aperture checks; r6 ICE fix).
// lane=(r_=lane&15 -> out idx, cch_=lane>>4 -> 32-col chunk), 2 shfl levels.
#define FC_SIM(FHP_OFF, OFC_TMP, T_TMP, NOTE, WRITE_RING, WRITE_OUT, TEMPO_VAL) do { \
    const int r_ = lane & 15; \
    const int cch_ = lane >> 4; \
    float a0_ = 0.f, a1_ = 0.f, a2_ = 0.f, a3_ = 0.f; \
    if (r_ < 10) { \
        const uint4* fv_ = (const uint4*)(fh_pk + (FHP_OFF)) + (cch_ << 2); \
        const uint4* wv_ = (const uint4*)(fcw_pk + r_ * 68) + (cch_ << 2); \
        _Pragma("unroll") \
        for (int q_ = 0; q_ < 4; q_++) { \
            uint4 aa_ = wv_[q_]; uint4 bb_ = fv_[q_]; \
            a0_ = fdot2f(aa_.x, bb_.x, a0_); \
            a1_ = fdot2f(aa_.y, bb_.y, a1_); \
            a2_ = fdot2f(aa_.z, bb_.z, a2_); \
            a3_ = fdot2f(aa_.w, bb_.w, a3_); \
        } \
    } \
    float acc_ = (a0_ + a1_) + (a2_ + a3_); \
    acc_ += __shfl_xor(acc_, 16); \
    acc_ += __shfl_xor(acc_, 32); \
    float ofc_ = acc_ + fcb_lds[r_]; \
    if (lane < 10) OFC_TMP[lane] = ofc_; \
    LGKM0(); \
    if (lane < 10) { \
        float a_ = attnb_lds[lane]; \
        _Pragma("unroll") \
        for (int c_ = 0; c_ < 10; c_++) a_ += attnW_lds[lane * 10 + c_] * OFC_TMP[c_]; \
        T_TMP[lane] = tanhc(a_) * attncv_lds[lane]; \
    } \
    LGKM0(); \
    if ((WRITE_RING) && lane == 0) { \
        float s_ = 0.f; \
        _Pragma("unroll") \
        for (int c_ = 0; c_ < 10; c_++) s_ += T_TMP[c_]; \
        sim_ring[(NOTE) & 255] = s_; \
    } \
    if (lane < 10) { \
        if (WRITE_RING) out_ring[((NOTE) & 255) * 10 + lane] = ofc_; \
        if (WRITE_OUT) out[(NOTE) * 11 + 1 + lane] = ofc_; \
    } \
    if ((WRITE_OUT) && lane == 0) out[(NOTE) * 11] = (TEMPO_VAL); \
} while (0)

// ---------------- 2000-step serial scan: one 512-thread workgroup ----------------
// waves_per_eu(2,2) PINS occupancy at 2 waves/SIMD -> 256-VGPR budget; the
// allocator has no incentive to spill the 128 weight regs (rounds 3-5 bug).
__global__ __launch_bounds__(512)
__attribute__((amdgpu_waves_per_eu(2, 2)))
void seq_kernel(
    const float* __restrict__ oWih, const float* __restrict__ oWhh,
    const float* __restrict__ tWih, const float* __restrict__ tWhh,
    const float* __restrict__ fcW, const float* __restrict__ fcb,
    const float* __restrict__ tfcW, const float* __restrict__ tfcb,
    const float* __restrict__ attnW, const float* __restrict__ attnb,
    const float* __restrict__ attncv,
    const int* __restrict__ bn_g,
    const float* __restrict__ opre, const float* __restrict__ tpre,
    float* __restrict__ out) {
    const int j = threadIdx.x;   // row 0..511
    const int lane = j & 63;

    __shared__ float z_lds[512];                 // [gate*128+unit] = row j
    __shared__ float zt_lds[512];
    __shared__ __align__(16) uint_t fh_pk[2 * 64];  // parity double-buffer
    __shared__ __align__(16) uint_t th_pk[64];
    __shared__ __align__(16) uint_t fcw_pk[10 * 68];
    __shared__ float attnW_lds[100];
    __shared__ float attnb_lds[10], attncv_lds[10];
    __shared__ float fcb_lds[16];                // padded: FC_SIM reads r_ in [0,16)
    __shared__ uint_t rn_pk[5];
    __shared__ float rn_tmp[10];
    __shared__ float tempo_lds[2];               // parity double-buffer
    __shared__ float ofc_tmpD[10], t_tmpD[10], ofc_tmpE[10], t_tmpE[10];
    __shared__ float out_ring[256 * 10];
    __shared__ float sim_ring[256];

    // ---- stage small tensors ----
    for (int idx = j; idx < 640; idx += 512) {
        int r = idx >> 6, k = idx & 63;
        fcw_pk[r * 68 + k] = pk2(fcW[r * 128 + 2 * k], fcW[r * 128 + 2 * k + 1]);
    }
    if (j < 100) attnW_lds[j] = attnW[j];
    if (j < 16) fcb_lds[j] = 0.f;
    if (j < 10) {
        attnb_lds[j] = attnb[j];
        attncv_lds[j] = attncv[j];
        fcb_lds[j] = fcb[j];
    }
    if (j < 5) rn_pk[j] = 0;
    if (j < 128) fh_pk[j] = 0;
    if (j < 64) th_pk[j] = 0;
    if (j < 2) tempo_lds[j] = 0.f;
    __syncthreads();

    // ---- per-thread FULL-row weights (register-resident) ----
    float c1[10];
#pragma unroll
    for (int r = 0; r < 10; r++) c1[r] = oWih[j * 715 + 641 + r];
    float d0 = 0.f;
#pragma unroll
    for (int r = 0; r < 10; r++) d0 += c1[r] * fcb_lds[r];
    const float ocol = oWih[j * 715 + 640];
    const float twc384 = tWih[j * 467 + 384];

    uvec32 w2a, w2b;
    {
        const float* owr = oWhh + j * 128;
#pragma unroll
        for (int q = 0; q < 32; q++) {
            float a = owr[2 * q], b = owr[2 * q + 1];
#pragma unroll
            for (int r = 0; r < 10; r++) {
                a += c1[r] * fcW[r * 128 + 2 * q];
                b += c1[r] * fcW[r * 128 + 2 * q + 1];
            }
            w2a[q] = pk2(a, b);
        }
#pragma unroll
        for (int q = 0; q < 32; q++) {
            float a = owr[64 + 2 * q], b = owr[64 + 2 * q + 1];
#pragma unroll
            for (int r = 0; r < 10; r++) {
                a += c1[r] * fcW[r * 128 + 64 + 2 * q];
                b += c1[r] * fcW[r * 128 + 64 + 2 * q + 1];
            }
            w2b[q] = pk2(a, b);
        }
    }
    uvec32 t2a, t2b;  // T2 = t_Whh + t_Wih[:,384] (x) tfcW  (tempo fold)
    {
        const float* twr = tWhh + j * 128;
#pragma unroll
        for (int q = 0; q < 32; q++)
            t2a[q] = pk2(twr[2 * q] + twc384 * tfcW[2 * q],
                         twr[2 * q + 1] + twc384 * tfcW[2 * q + 1]);
#pragma unroll
        for (int q = 0; q < 32; q++)
            t2b[q] = pk2(twr[64 + 2 * q] + twc384 * tfcW[64 + 2 * q],
                         twr[64 + 2 * q + 1] + twc384 * tfcW[64 + 2 * q + 1]);
    }
    uint_t twcp[5];
#pragma unroll
    for (int r = 0; r < 5; r++)
        twcp[r] = pk2(tWih[j * 467 + 393 + 2 * r], tWih[j * 467 + 393 + 2 * r + 1]);
    const float const_t = twc384 * tfcb[0];

    // wave-0 lane constants for tempo reduce
    const float tfcwA = tfcW[2 * lane], tfcwB = tfcW[2 * lane + 1];
    const float tfcb_s = tfcb[0];

    // ---- recurrence state ----
    float fc0 = 0.f, fc1 = 0.f, tc0 = 0.f, tc1 = 0.f;  // wave-0 lanes
    float tempo_reg = 0.f;                              // wave-0 lanes
    int prev_end = 0;                                   // wave-0
    int bn_cur = bn_g[0];
    int bn_nxt = bn_g[1];
    bool bnd_cur = true;
    float pre_o = opre[j];
    float pre_t = tpre[j];
    __syncthreads();

#pragma unroll 1
    for (int i = 0; i < N_NOTES; ++i) {
        const bool bnd_nxt = (bn_nxt > bn_cur);
        const int par = i & 1;
        // ---- depth-1 prefetch (raw barriers never drain vmcnt) ----
        float pre_o_nxt = 0.f, pre_t_nxt = 0.f;
        int bn_nxt2 = bn_nxt;
        if (i + 1 < N_NOTES) {
            pre_o_nxt = opre[(i + 1) * 512 + j];
            if (bnd_nxt) pre_t_nxt = tpre[(i + 1) * 512 + j];
            if (i + 2 < N_NOTES) bn_nxt2 = bn_g[i + 2];
        }
        // ---- P1: full-row matvecs (all 512 threads) ----
        {
            float zb = pre_o + ocol * tempo_lds[par ^ 1];
            if (i == 0) zb -= d0;
            const uint4* fp = (const uint4*)(fh_pk + ((par ^ 1) << 6));
            float a0 = zb, a1 = 0.f, a2 = 0.f, a3 = 0.f;
#pragma unroll
            for (int q = 0; q < 8; q++) {
                uint4 v = fp[q];
                a0 = fdot2f(w2a[4 * q + 0], v.x, a0);
                a1 = fdot2f(w2a[4 * q + 1], v.y, a1);
                a2 = fdot2f(w2a[4 * q + 2], v.z, a2);
                a3 = fdot2f(w2a[4 * q + 3], v.w, a3);
            }
#pragma unroll
            for (int q = 0; q < 8; q++) {
                uint4 v = fp[8 + q];
                a0 = fdot2f(w2b[4 * q + 0], v.x, a0);
                a1 = fdot2f(w2b[4 * q + 1], v.y, a1);
                a2 = fdot2f(w2b[4 * q + 2], v.z, a2);
                a3 = fdot2f(w2b[4 * q + 3], v.w, a3);
            }
            z_lds[j] = (a0 + a1) + (a2 + a3);
        }
        if (bnd_cur) {
            float ztb = (i == 0) ? 0.f : const_t;
#pragma unroll
            for (int r = 0; r < 5; r++) ztb = fdot2f(twcp[r], rn_pk[r], ztb);
            const uint4* tp = (const uint4*)th_pk;
            float a0 = pre_t + ztb, a1 = 0.f, a2 = 0.f, a3 = 0.f;
#pragma unroll
            for (int q = 0; q < 8; q++) {
                uint4 v = tp[q];
                a0 = fdot2f(t2a[4 * q + 0], v.x, a0);
                a1 = fdot2f(t2a[4 * q + 1], v.y, a1);
                a2 = fdot2f(t2a[4 * q + 2], v.z, a2);
                a3 = fdot2f(t2a[4 * q + 3], v.w, a3);
            }
#pragma unroll
            for (int q = 0; q < 8; q++) {
                uint4 v = tp[8 + q];
                a0 = fdot2f(t2b[4 * q + 0], v.x, a0);
                a1 = fdot2f(t2b[4 * q + 1], v.y, a1);
                a2 = fdot2f(t2b[4 * q + 2], v.z, a2);
                a3 = fdot2f(t2b[4 * q + 3], v.w, a3);
            }
            zt_lds[j] = (a0 + a1) + (a2 + a3);
        }
        BAR();  // BAR1: z/zt visible
        // ---- P2: wave0 gates+tempo; wave1 deferred fc/out for note i-1 ----
        if (j < 64) {
            const int u0 = 2 * lane;
            float2 zi = *(const float2*)&z_lds[u0];
            float2 zf = *(const float2*)&z_lds[128 + u0];
            float2 zg = *(const float2*)&z_lds[256 + u0];
            float2 zo = *(const float2*)&z_lds[384 + u0];
            fc0 = sigm(zf.x) * fc0 + sigm(zi.x) * tanhc(zg.x);
            fc1 = sigm(zf.y) * fc1 + sigm(zi.y) * tanhc(zg.y);
            float h0 = sigm(zo.x) * tanhc(fc0);
            float h1 = sigm(zo.y) * tanhc(fc1);
            fh_pk[(par << 6) + lane] = pk2(h0, h1);
            if (bnd_cur) {
                float2 ti = *(const float2*)&zt_lds[u0];
                float2 tf = *(const float2*)&zt_lds[128 + u0];
                float2 tg = *(const float2*)&zt_lds[256 + u0];
                float2 to = *(const float2*)&zt_lds[384 + u0];
                tc0 = sigm(tf.x) * tc0 + sigm(ti.x) * tanhc(tg.x);
                tc1 = sigm(tf.y) * tc1 + sigm(ti.y) * tanhc(tg.y);
                float g0 = sigm(to.x) * tanhc(tc0);
                float g1 = sigm(to.y) * tanhc(tc1);
                th_pk[lane] = pk2(g0, g1);
                float q = tfcwA * g0 + tfcwB * g1;
#pragma unroll
                for (int d = 32; d >= 1; d >>= 1) q += __shfl_xor(q, d);
                tempo_reg = q + tfcb_s;
                prev_end = i;
            }
            if (lane == 0) tempo_lds[par] = tempo_reg;
        } else if (j < 128 && i > 0) {
            FC_SIM(((par ^ 1) << 6), ofc_tmpD, t_tmpD, i - 1, !bnd_cur, true, tempo_lds[par ^ 1]);
        }
        BAR();  // BAR2
        // ---- P3 (pre-boundary steps only): wave0 eager fc + attention -> rn ----
        if (bnd_nxt && (i + 1 < N_NOTES)) {
            if (j < 64) {
                FC_SIM((par << 6), ofc_tmpE, t_tmpE, i, true, false, 0.f);
                LGKM0();
                const int L = i + 1 - prev_end;
                float m = -1e30f;
                for (int b = lane; b < L; b += 64) m = fmaxf(m, sim_ring[(prev_end + b) & 255]);
#pragma unroll
                for (int d = 32; d >= 1; d >>= 1) m = fmaxf(m, __shfl_xor(m, d));
                float es = 0.f;
                float accv[10];
#pragma unroll
                for (int r = 0; r < 10; r++) accv[r] = 0.f;
                for (int b = lane; b < L; b += 64) {
                    int idx = (prev_end + b) & 255;
                    float e = __expf(sim_ring[idx] - m);
                    es += e;
#pragma unroll
                    for (int r = 0; r < 10; r++) accv[r] += e * out_ring[idx * 10 + r];
                }
#pragma unroll
                for (int d = 32; d >= 1; d >>= 1) {
                    es += __shfl_xor(es, d);
#pragma unroll
                    for (int r = 0; r < 10; r++) accv[r] += __shfl_xor(accv[r], d);
                }
                float inv = 1.f / fmaxf(es, 1e-20f);
                if (lane < 10) rn_tmp[lane] = accv[lane] * inv;
                LGKM0();
                if (lane < 5) rn_pk[lane] = pk2(rn_tmp[2 * lane], rn_tmp[2 * lane + 1]);
            }
            BAR();  // BAR3: rn visible for next P1
        }
        pre_o = pre_o_nxt;
        pre_t = bnd_nxt ? pre_t_nxt : pre_t;
        bn_cur = bn_nxt;
        bn_nxt = bn_nxt2;
        bnd_cur = bnd_nxt;
    }
    // epilogue: deferred output for the final note
    if (j >= 64 && j < 128) {
        FC_SIM((((N_NOTES - 1) & 1) << 6), ofc_tmpD, t_tmpD, N_NOTES - 1, false, true,
               tempo_lds[(N_NOTES - 1) & 1]);
    }
}

extern "C" void kernel_launch(void* const* d_in, const int* in_sizes, int n_in,
                              void* d_out, int out_size, void* d_ws, size_t ws_size,
                              hipStream_t stream) {
    (void)in_sizes; (void)n_in; (void)out_size; (void)ws_size;
    const float* ne     = (const float*)d_in[0];
    const float* be     = (const float*)d_in[1];
    const float* me     = (const float*)d_in[2];
    const float* ri     = (const float*)d_in[3];
    const float* perf   = (const float*)d_in[4];
    const int*   bn     = (const int*)d_in[5];
    const int*   mn     = (const int*)d_in[6];
    const float* expW   = (const float*)d_in[7];
    const float* expb   = (const float*)d_in[8];
    const float* tWih   = (const float*)d_in[9];
    const float* tWhh   = (const float*)d_in[10];
    const float* tbih   = (const float*)d_in[11];
    const float* tbhh   = (const float*)d_in[12];
    const float* tfcW   = (const float*)d_in[13];
    const float* tfcb   = (const float*)d_in[14];
    const float* attnW  = (const float*)d_in[15];
    const float* attnb  = (const float*)d_in[16];
    const float* attncv = (const float*)d_in[17];
    const float* oWih   = (const float*)d_in[18];
    const float* oWhh   = (const float*)d_in[19];
    const float* obih   = (const float*)d_in[20];
    const float* obhh   = (const float*)d_in[21];
    const float* fcW    = (const float*)d_in[22];
    const float* fcb    = (const float*)d_in[23];

    float* pz   = (float*)d_ws;
    float* opre = pz + 64;
    float* tpre = opre + N_NOTES * 512;
    float* out  = (float*)d_out;

    pz_kernel<<<1, 64, 0, stream>>>(expW, expb, perf, pz);
    opre_kernel<<<N_NOTES / 16, 512, 0, stream>>>(oWih, obih, obhh, ne, be, me, fcb, pz, bn, mn, opre);
    tpre_kernel<<<N_NOTES / 16, 512, 0, stream>>>(tWih, tbih, tbhh, be, me, ri, pz, bn, mn, tpre);
    seq_kernel<<<1, 512, 0, stream>>>(oWih, oWhh, tWih, tWhh, fcW, fcb, tfcW, tfcb,
                                      attnW, attnb, attncv, bn, opre, tpre, out);
}